// Round 5
// baseline (24.302 us; speedup 1.0000x reference)
//
#include <hip/hip_runtime.h>

// constant_current_lif_encode, bit-exact vs float32 reference:
//   v <- v + 0.1f*((0 - v) + I)   ; each op individually rounded, NO fma
//   z <- (v > 1.0f)               ; exact heaviside(v-1) by Sterbenz
//   v <- 0 on spike               ; exact (v - 1*(v-0) = 0)
//
// Round 5: R3 structure (2-way time split, 32 waves/CU, scalar stores — best
// at 21.4 us) + NONTEMPORAL stores. The 105 MB output is write-once and
// never re-read; regular stores allocate L2/L3 lines that the kernel-end
// coherence flush must write back. `nt` stores stream past the caches —
// the profile of the 6.8 TB/s fill kernel. Width/occupancy are exhausted
// (R1-R4 matrix); cache policy is the last orthogonal lever.
//
// Exactness: reset hits exactly 0.0f (= initial state), and h=1 replays the
// identical rounded op sequence, so its v at t=50 is bit-identical to h=0's
// continuation. _rn intrinsics forbid FMA contraction.

#define LIF_HALF 50

__global__ __launch_bounds__(256)
void ConstantCurrentLIFEncoder_10436770530031_kernel(
    const float* __restrict__ in, float* __restrict__ out, int n)
{
    const int tid = blockIdx.x * blockDim.x + threadIdx.x;
    const int i = tid & (n - 1);        // neuron index (n = 262144, power of two)
    const int h = tid >= n;             // time half: 0 or 1

    const float I = in[i];
    float v = 0.0f;

    if (h) {
        // replay first half, no stores — bit-identical trajectory
        #pragma unroll
        for (int t = 0; t < LIF_HALF; ++t) {
            v = __fadd_rn(v, __fmul_rn(0.1f, __fsub_rn(I, v)));
            if (v > 1.0f) v = 0.0f;
        }
    }

    float* __restrict__ o = out + (size_t)(h ? LIF_HALF : 0) * (size_t)n + (size_t)i;

    #pragma unroll
    for (int t = 0; t < LIF_HALF; ++t) {
        v = __fadd_rn(v, __fmul_rn(0.1f, __fsub_rn(I, v)));
        const bool spike = (v > 1.0f);
        __builtin_nontemporal_store(spike ? 1.0f : 0.0f, &o[(size_t)t * (size_t)n]);
        if (spike) v = 0.0f;
    }
}

extern "C" void kernel_launch(void* const* d_in, const int* in_sizes, int n_in,
                              void* d_out, int out_size, void* d_ws, size_t ws_size,
                              hipStream_t stream) {
    const float* in = (const float*)d_in[0];
    float* out = (float*)d_out;
    const int n = in_sizes[0];              // 262144 (power of two)
    const int block = 256;
    const int grid = (2 * n) / block;       // 2048 blocks -> 32 waves/CU
    ConstantCurrentLIFEncoder_10436770530031_kernel<<<grid, block, 0, stream>>>(in, out, n);
}

// Round 6
// 21.085 us; speedup vs baseline: 1.1526x; 1.1526x over previous
//
#include <hip/hip_runtime.h>

// constant_current_lif_encode, bit-exact vs float32 reference:
//   v <- v + 0.1f*((0 - v) + I)   ; each op individually rounded, NO fma
//   z <- (v > 1.0f)               ; exact heaviside(v-1) by Sterbenz
//   v <- 0 on spike               ; exact (v - 1*(v-0) = 0)
//
// FINAL (revert to round-3 best, 21.4 us): 2-way time split, scalar stores,
// 32 waves/CU. Thread (i, h) owns neuron i and timestep half h:
//   h=0: simulate+store t = 0..49
//   h=1: simulate t = 0..49 (VALU only, bit-identical), then store t = 50..99
//
// Exploration matrix (R1-R5): store width {dword, dwordx4}, occupancy
// {4,16,32 waves/CU}, time split {1,2,4}, cache policy {cached, nt}.
// Best = this kernel. Arithmetic: 104.9 MB write-compulsory @ 6.8 TB/s
// achievable = 15.4 us + ~6 us fixed (graph launch + 8192-wave ramp + tail,
// unamortizable at this transfer size) = 21.4 us observed. nt stores
// REGRESS 13% on gfx950 (L2 writeback path outperforms direct-to-HBM).
//
// Exactness: reset hits exactly 0.0f (= initial state), and h=1 replays the
// identical rounded op sequence, so its v at t=50 is bit-identical to h=0's
// continuation. _rn intrinsics forbid FMA contraction (rounding change could
// shift a spike by one timestep; threshold is 2e-2 on 0/1 data).

#define LIF_HALF 50

__global__ __launch_bounds__(256)
void ConstantCurrentLIFEncoder_10436770530031_kernel(
    const float* __restrict__ in, float* __restrict__ out, int n)
{
    const int tid = blockIdx.x * blockDim.x + threadIdx.x;
    const int i = tid & (n - 1);        // neuron index (n = 262144, power of two)
    const int h = tid >= n;             // time half: 0 or 1

    const float I = in[i];
    float v = 0.0f;

    if (h) {
        // replay first half, no stores — bit-identical trajectory
        #pragma unroll
        for (int t = 0; t < LIF_HALF; ++t) {
            v = __fadd_rn(v, __fmul_rn(0.1f, __fsub_rn(I, v)));
            if (v > 1.0f) v = 0.0f;
        }
    }

    float* __restrict__ o = out + (size_t)(h ? LIF_HALF : 0) * (size_t)n + (size_t)i;

    #pragma unroll
    for (int t = 0; t < LIF_HALF; ++t) {
        v = __fadd_rn(v, __fmul_rn(0.1f, __fsub_rn(I, v)));
        const bool spike = (v > 1.0f);
        o[(size_t)t * (size_t)n] = spike ? 1.0f : 0.0f;
        if (spike) v = 0.0f;
    }
}

extern "C" void kernel_launch(void* const* d_in, const int* in_sizes, int n_in,
                              void* d_out, int out_size, void* d_ws, size_t ws_size,
                              hipStream_t stream) {
    const float* in = (const float*)d_in[0];
    float* out = (float*)d_out;
    const int n = in_sizes[0];              // 262144 (power of two)
    const int block = 256;
    const int grid = (2 * n) / block;       // 2048 blocks -> 32 waves/CU
    ConstantCurrentLIFEncoder_10436770530031_kernel<<<grid, block, 0, stream>>>(in, out, n);
}